// Round 4
// baseline (2709.951 us; speedup 1.0000x reference)
//
#include <hip/hip_runtime.h>
#include <math.h>

// ResidualQuantizer: 8 stages of VQ over B=32768 rows, D=256, K=1024.
// Outputs (flat f32): z_q_sum[32768*256], codes[32768*8] (as float), loss[1].
// Numerics: bit-exact numpy fp32 emulation for the argmin (proven r2/r3):
//   dist = fl(fl(z2 + e2_k) - 2*ze_k), ze_k = ascending-d fp32 FMA chain,
//   e2_k = numpy pairwise sum, argmin = first occurrence of min.
// Round 4: (a) wave pairs split the 512-code pass (16 rows x 4 codes/lane)
//   -> LDS E-read traffic halved; (b) double-buffered KC=8 staging with
//   issue-before-compute -> staging latency hidden under fmaf.

#define NQ 8
#define KCODES 1024
#define DDIM 256
#define BN 32768
#define TM 32            // rows per block
#define THREADS 256
#define KC 8             // k elements staged per chunk
#define NCHUNK (DDIM / KC)   // 32
#define CPP 512          // codes per pass
#define NPASS 2

__device__ __forceinline__ void gld_lds16(const void* g, void* l) {
    __builtin_amdgcn_global_load_lds(
        (const __attribute__((address_space(1))) unsigned int*)g,
        (__attribute__((address_space(3))) unsigned int*)l, 16, 0, 0);
}

// ---- e2[s*K+k] = np.sum(cb[s][k]**2), exact numpy pairwise emulation ----
__global__ void e2_kernel(const float* __restrict__ cb, float* __restrict__ e2) {
    __shared__ float X[16][DDIM];
    const int t = threadIdx.x;
    const int cbase = blockIdx.x * 16;
    {
        const float4* src = (const float4*)(cb + (size_t)cbase * DDIM);
        float4* dst = (float4*)(&X[0][0]);
        #pragma unroll
        for (int n = 0; n < 4; ++n) dst[t + n * THREADS] = src[t + n * THREADS];
    }
    __syncthreads();
    const int lane = t & 63;
    const int code = (t >> 6) * 4 + (lane >> 4);
    const int u = lane & 15, j = u & 7, h = u >> 3;
    const float* x = &X[code][h * 128];
    float r = __fmul_rn(x[j], x[j]);
    for (int i = 1; i < 16; ++i) {
        float v = x[8 * i + j];
        r = __fadd_rn(r, __fmul_rn(v, v));
    }
    float o;
    o = __shfl_xor(r, 1); r = __fadd_rn(r, o);
    o = __shfl_xor(r, 2); r = __fadd_rn(r, o);
    o = __shfl_xor(r, 4); r = __fadd_rn(r, o);
    o = __shfl_xor(r, 8); r = __fadd_rn(r, o);
    if (u == 0) e2[cbase + code] = r;
}

__global__ __launch_bounds__(THREADS, 2) void rq_kernel(
    const float* __restrict__ zin, const float* __restrict__ cb,
    const float* __restrict__ e2g, float* __restrict__ out,
    double* __restrict__ lossp)
{
    __shared__ float  Rs[TM][DDIM];        // 32 KB residual tile (persistent)
    __shared__ float4 Es[2][1024];         // 2 x 16 KB codebook chunk, dbuf
    __shared__ float  top1v[NPASS][2][TM];
    __shared__ int    top1i[NPASS][2][TM];
    __shared__ float  z2s[TM];
    __shared__ int    codes_s[TM];
    __shared__ double lred[THREADS];

    const int t    = threadIdx.x;
    const int l    = t & 63;
    const int w    = t >> 6;               // wave id 0..3
    const int h    = w >> 1;               // code half: waves 0,1 -> codes [0,256)
    const int wr   = w & 1;                // row half: rows wr*16 .. wr*16+15
    const size_t rowbase = (size_t)blockIdx.x * TM;
    const int row_u = t >> 3, oct = t & 7;
    const int sq0  = (l >> 2) & 1;          // ev read-side swizzle bit
    const int evb  = h * 512 + l * 2;       // ev slot base
    // staging source: unit u = n*256+t -> code ec = n*128+(t>>1),
    // content part p = (u&1)^((u>>3)&1) (pre-swizzled source, linear LDS dest)
    const size_t pbase = (size_t)(t >> 1) * DDIM + (((t & 1) ^ ((t >> 3) & 1)) << 2);

    // ---- load residual tile = z_e rows (coalesced) ----
    {
        const float4* src = (const float4*)(zin + rowbase * DDIM);
        float4* dst = (float4*)(&Rs[0][0]);
        #pragma unroll
        for (int n = 0; n < (TM * DDIM / 4) / THREADS; ++n)
            dst[t + n * THREADS] = src[t + n * THREADS];
    }
    __syncthreads();

    // ---- initial z2 per row (identical to r3: uniform shift, any order OK) ----
    {
        const float4* rrow = (const float4*)(&Rs[row_u][oct * 32]);
        float z2n = 0.f;
        #pragma unroll
        for (int i = 0; i < 8; ++i) {
            float4 rv = rrow[i];
            z2n = fmaf(rv.x, rv.x, z2n); z2n = fmaf(rv.y, rv.y, z2n);
            z2n = fmaf(rv.z, rv.z, z2n); z2n = fmaf(rv.w, rv.w, z2n);
        }
        z2n += __shfl_xor(z2n, 1);
        z2n += __shfl_xor(z2n, 2);
        z2n += __shfl_xor(z2n, 4);
        if (oct == 0) z2s[row_u] = z2n;
    }
    double lacc = 0.0;

    for (int s = 0; s < NQ; ++s) {
        const float* cbs = cb + (size_t)s * KCODES * DDIM;

        for (int p = 0; p < NPASS; ++p) {
            const int code0 = p * CPP;
            const float* sb = cbs + (size_t)code0 * DDIM + pbase;

            float acc[16][4];
            #pragma unroll
            for (int i = 0; i < 16; ++i)
                #pragma unroll
                for (int j = 0; j < 4; ++j) acc[i][j] = 0.f;

            float e2v[4];
            #pragma unroll
            for (int j = 0; j < 4; ++j)
                e2v[j] = e2g[s * KCODES + code0 + h * 256 + j * 64 + l];

            // ---- stage chunk 0 into buf 0 ----
            #pragma unroll
            for (int n = 0; n < 4; ++n)
                gld_lds16(sb + (size_t)n * 128 * DDIM, &Es[0][n * 256 + w * 64]);
            __syncthreads();

            for (int c = 0; c < NCHUNK; ++c) {
                const int buf = c & 1;
                // issue next chunk's staging BEFORE compute (latency hides)
                if (c + 1 < NCHUNK) {
                    #pragma unroll
                    for (int n = 0; n < 4; ++n)
                        gld_lds16(sb + (size_t)n * 128 * DDIM + (c + 1) * KC,
                                  &Es[buf ^ 1][n * 256 + w * 64]);
                }
                // ascending-d fp32 FMA chain (identical arithmetic to r2/r3)
                #pragma unroll
                for (int q = 0; q < 2; ++q) {
                    float4 ev[4];
                    #pragma unroll
                    for (int j = 0; j < 4; ++j)
                        ev[j] = Es[buf][evb + j * 128 + (q ^ sq0)];
                    #pragma unroll
                    for (int i = 0; i < 16; ++i) {
                        float4 rv = *(const float4*)(&Rs[wr * 16 + i][c * KC + q * 4]);
                        #pragma unroll
                        for (int j = 0; j < 4; ++j) {
                            acc[i][j] = fmaf(rv.x, ev[j].x, acc[i][j]);
                            acc[i][j] = fmaf(rv.y, ev[j].y, acc[i][j]);
                            acc[i][j] = fmaf(rv.z, ev[j].z, acc[i][j]);
                            acc[i][j] = fmaf(rv.w, ev[j].w, acc[i][j]);
                        }
                    }
                }
                __syncthreads();   // staged data visible; cur buf free to overwrite
            }

            // ---- per-row top-1, numpy-exact dist & first-occurrence ties ----
            #pragma unroll
            for (int i = 0; i < 16; ++i) {
                float z2i = z2s[wr * 16 + i];
                float m1 = 3.4e38f; int i1 = 0x7fffffff;
                #pragma unroll
                for (int j = 0; j < 4; ++j) {
                    float S = __fadd_rn(z2i, e2v[j]);      // fl(z2 + e2)
                    float v = fmaf(-2.f, acc[i][j], S);    // fl(S - 2*ze)
                    int cc = code0 + h * 256 + j * 64 + l;
                    if (v < m1) { m1 = v; i1 = cc; }       // ascending cc keeps first
                }
                #pragma unroll
                for (int d2 = 1; d2 < 64; d2 <<= 1) {
                    float ov = __shfl_xor(m1, d2); int oi = __shfl_xor(i1, d2);
                    if (ov < m1 || (ov == m1 && oi < i1)) { m1 = ov; i1 = oi; }
                }
                if (l == i) { top1v[p][h][wr * 16 + i] = m1;
                              top1i[p][h][wr * 16 + i] = i1; }
            }
            __syncthreads();
        }

        // ---- merge 4 partials in ascending index order, emit code ----
        if (t < TM) {
            float m1 = top1v[0][0][t]; int i1 = top1i[0][0][t];
            float v;
            v = top1v[0][1][t]; if (v < m1) { m1 = v; i1 = top1i[0][1][t]; }
            v = top1v[1][0][t]; if (v < m1) { m1 = v; i1 = top1i[1][0][t]; }
            v = top1v[1][1][t]; if (v < m1) { m1 = v; i1 = top1i[1][1][t]; }
            codes_s[t] = i1;
            out[(size_t)BN * DDIM + (rowbase + t) * NQ + s] = (float)i1;
        }
        __syncthreads();

        // ---- straight-through update, op-for-op numpy emulation (as r3) ----
        {
            int c = codes_s[row_u];
            const float4* crow = (const float4*)(cbs + (size_t)c * DDIM + oct * 32);
            float4* rrow = (float4*)(&Rs[row_u][oct * 32]);
            float z2n = 0.f;
            #pragma unroll
            for (int n = 0; n < 8; ++n) {
                int i = (n + t) & 7;              // rotate -> spread LDS banks
                float4 rv = rrow[i];
                float4 cv = crow[i];
                float t1x = __fsub_rn(cv.x, rv.x), t1y = __fsub_rn(cv.y, rv.y);
                float t1z = __fsub_rn(cv.z, rv.z), t1w = __fsub_rn(cv.w, rv.w);
                lacc += (double)t1x * t1x + (double)t1y * t1y
                      + (double)t1z * t1z + (double)t1w * t1w;
                float qx = __fadd_rn(rv.x, t1x), qy = __fadd_rn(rv.y, t1y);
                float qz = __fadd_rn(rv.z, t1z), qw = __fadd_rn(rv.w, t1w);
                float nx = __fsub_rn(rv.x, qx), ny = __fsub_rn(rv.y, qy);
                float nz = __fsub_rn(rv.z, qz), nw = __fsub_rn(rv.w, qw);
                z2n = fmaf(nx, nx, z2n); z2n = fmaf(ny, ny, z2n);
                z2n = fmaf(nz, nz, z2n); z2n = fmaf(nw, nw, z2n);
                rrow[i] = make_float4(nx, ny, nz, nw);
            }
            z2n += __shfl_xor(z2n, 1);
            z2n += __shfl_xor(z2n, 2);
            z2n += __shfl_xor(z2n, 4);
            if (oct == 0) z2s[row_u] = z2n;
        }
        __syncthreads();
    }

    // ---- z_q_sum = z_e - residual_final (telescoped; tolerance-validated) ----
    {
        const float4* zsrc = (const float4*)(zin + rowbase * DDIM);
        const float4* rsrc = (const float4*)(&Rs[0][0]);
        float4* dst = (float4*)(out + rowbase * DDIM);
        #pragma unroll
        for (int n = 0; n < (TM * DDIM / 4) / THREADS; ++n) {
            int idx = t + n * THREADS;
            float4 a = zsrc[idx], r = rsrc[idx];
            a.x -= r.x; a.y -= r.y; a.z -= r.z; a.w -= r.w;
            dst[idx] = a;
        }
    }

    // ---- deterministic per-block loss partial ----
    lred[t] = lacc;
    __syncthreads();
    if (t == 0) {
        double sum = 0.0;
        for (int i = 0; i < THREADS; ++i) sum += lred[i];
        lossp[blockIdx.x] = sum;
    }
}

__global__ void loss_final(const double* __restrict__ lossp, float* __restrict__ out) {
    double s = 0.0;
    for (int i = 0; i < BN / TM; ++i) s += lossp[i];
    out[(size_t)BN * DDIM + (size_t)BN * NQ] = (float)(1.25 * s / ((double)BN * (double)DDIM));
}

extern "C" void kernel_launch(void* const* d_in, const int* in_sizes, int n_in,
                              void* d_out, int out_size, void* d_ws, size_t ws_size,
                              hipStream_t stream) {
    const float* z_e = (const float*)d_in[0];
    const float* cb  = (const float*)d_in[1];
    float* out = (float*)d_out;
    float*  e2    = (float*)d_ws;                          // 8192 floats
    double* lossp = (double*)((char*)d_ws + 8192 * 4);     // 1024 doubles

    e2_kernel<<<dim3((NQ * KCODES) / 16), THREADS, 0, stream>>>(cb, e2);
    rq_kernel<<<dim3(BN / TM), THREADS, 0, stream>>>(z_e, cb, e2, out, lossp);
    loss_final<<<1, 1, 0, stream>>>(lossp, out);
}

// Round 5
// 2066.134 us; speedup vs baseline: 1.3116x; 1.3116x over previous
//
#include <hip/hip_runtime.h>
#include <math.h>

// ResidualQuantizer: 8 stages of VQ over B=32768 rows, D=256, K=1024.
// Outputs (flat f32): z_q_sum[32768*256], codes[32768*8] (as float), loss[1].
// Numerics: bit-exact numpy fp32 emulation for the argmin (proven r2/r3):
//   dist = fl(fl(z2 + e2_k) - 2*ze_k), ze_k = ascending-d fp32 FMA chain,
//   e2_k = numpy pairwise sum, argmin = first occurrence of min.
// Round 5: r3 compute shape (8 rows x 8 codes/lane) + TRUE pipeline:
//   raw s_barrier (no vmcnt(0) drain of in-flight prefetch), stage-after-
//   barrier into KC=8 double buffer. Only stale loads are waited.

#define NQ 8
#define KCODES 1024
#define DDIM 256
#define BN 32768
#define TM 32            // rows per block
#define THREADS 256
#define KC 8             // k elements staged per chunk
#define NCHUNK (DDIM / KC)   // 32
#define CPP 512          // codes per pass
#define NPASS 2

__device__ __forceinline__ void gld_lds16(const void* g, void* l) {
    __builtin_amdgcn_global_load_lds(
        (const __attribute__((address_space(1))) unsigned int*)g,
        (__attribute__((address_space(3))) unsigned int*)l, 16, 0, 0);
}

// ---- e2[s*K+k] = np.sum(cb[s][k]**2), exact numpy pairwise emulation ----
__global__ void e2_kernel(const float* __restrict__ cb, float* __restrict__ e2) {
    __shared__ float X[16][DDIM];
    const int t = threadIdx.x;
    const int cbase = blockIdx.x * 16;
    {
        const float4* src = (const float4*)(cb + (size_t)cbase * DDIM);
        float4* dst = (float4*)(&X[0][0]);
        #pragma unroll
        for (int n = 0; n < 4; ++n) dst[t + n * THREADS] = src[t + n * THREADS];
    }
    __syncthreads();
    const int lane = t & 63;
    const int code = (t >> 6) * 4 + (lane >> 4);
    const int u = lane & 15, j = u & 7, h = u >> 3;
    const float* x = &X[code][h * 128];
    float r = __fmul_rn(x[j], x[j]);
    for (int i = 1; i < 16; ++i) {
        float v = x[8 * i + j];
        r = __fadd_rn(r, __fmul_rn(v, v));
    }
    float o;
    o = __shfl_xor(r, 1); r = __fadd_rn(r, o);
    o = __shfl_xor(r, 2); r = __fadd_rn(r, o);
    o = __shfl_xor(r, 4); r = __fadd_rn(r, o);
    o = __shfl_xor(r, 8); r = __fadd_rn(r, o);
    if (u == 0) e2[cbase + code] = r;
}

__global__ __launch_bounds__(THREADS, 2) void rq_kernel(
    const float* __restrict__ zin, const float* __restrict__ cb,
    const float* __restrict__ e2g, float* __restrict__ out,
    double* __restrict__ lossp)
{
    __shared__ float  Rs[TM][DDIM];        // 32 KB residual tile (persistent)
    __shared__ float4 Es[2][1024];         // 2 x 16 KB codebook k-window, dbuf
    __shared__ float  top1v[NPASS][TM];
    __shared__ int    top1i[NPASS][TM];
    __shared__ float  z2s[TM];
    __shared__ int    codes_s[TM];
    __shared__ double lred[THREADS];

    const int t    = threadIdx.x;
    const int l    = t & 63;
    const int w    = t >> 6;               // wave id; wave w owns rows w*8..w*8+7
    const size_t rowbase = (size_t)blockIdx.x * TM;
    const int row_u = t >> 3, oct = t & 7;
    const int sq2  = (l >> 2) & 1;          // ev read-side swizzle bit
    // staging: unit u = n*256 + t; code ec = u>>1; stored part s = u&1 holds
    // content part p = (u&1)^((u>>3)&1) (pre-swizzled source, linear LDS dest)
    const size_t pbase = (size_t)(t >> 1) * DDIM + (((t & 1) ^ ((t >> 3) & 1)) << 2);

    // ---- load residual tile = z_e rows (coalesced) ----
    {
        const float4* src = (const float4*)(zin + rowbase * DDIM);
        float4* dst = (float4*)(&Rs[0][0]);
        #pragma unroll
        for (int n = 0; n < (TM * DDIM / 4) / THREADS; ++n)
            dst[t + n * THREADS] = src[t + n * THREADS];
    }
    __syncthreads();

    // ---- initial z2 per row (uniform shift: any fp32 order OK — proven) ----
    {
        const float4* rrow = (const float4*)(&Rs[row_u][oct * 32]);
        float z2n = 0.f;
        #pragma unroll
        for (int i = 0; i < 8; ++i) {
            float4 rv = rrow[i];
            z2n = fmaf(rv.x, rv.x, z2n); z2n = fmaf(rv.y, rv.y, z2n);
            z2n = fmaf(rv.z, rv.z, z2n); z2n = fmaf(rv.w, rv.w, z2n);
        }
        z2n += __shfl_xor(z2n, 1);
        z2n += __shfl_xor(z2n, 2);
        z2n += __shfl_xor(z2n, 4);
        if (oct == 0) z2s[row_u] = z2n;
    }
    double lacc = 0.0;

    for (int s = 0; s < NQ; ++s) {
        const float* cbs = cb + (size_t)s * KCODES * DDIM;

        for (int p = 0; p < NPASS; ++p) {
            const int code0 = p * CPP;
            const float* sb = cbs + (size_t)code0 * DDIM + pbase;

            float acc[8][8];
            #pragma unroll
            for (int i = 0; i < 8; ++i)
                #pragma unroll
                for (int j = 0; j < 8; ++j) acc[i][j] = 0.f;

            // ---- prologue: stage k-window 0 into buf 0 ----
            #pragma unroll
            for (int n = 0; n < 4; ++n)
                gld_lds16(sb + (size_t)n * 128 * DDIM, &Es[0][n * 256 + w * 64]);

            #pragma unroll 2
            for (int c = 0; c < NCHUNK; ++c) {
                // wait only STALE loads (chunk c, issued one iteration ago),
                // then raw barrier: chunk c published; buf[(c+1)&1] reads done.
                asm volatile("s_waitcnt vmcnt(0)" ::: "memory");
                __builtin_amdgcn_s_barrier();
                asm volatile("" ::: "memory");
                __builtin_amdgcn_sched_barrier(0);

                const int buf = c & 1;
                if (c + 1 < NCHUNK) {   // prefetch stays in flight across barrier
                    const float* src = sb + (c + 1) * KC;
                    #pragma unroll
                    for (int n = 0; n < 4; ++n)
                        gld_lds16(src + (size_t)n * 128 * DDIM,
                                  &Es[buf ^ 1][n * 256 + w * 64]);
                }

                // ascending-d fp32 FMA chain (identical arithmetic to r2/r3)
                #pragma unroll
                for (int q = 0; q < 2; ++q) {
                    float4 ev[8];
                    #pragma unroll
                    for (int j = 0; j < 8; ++j)
                        ev[j] = Es[buf][(j * 64 + l) * 2 + (q ^ sq2)];
                    #pragma unroll
                    for (int i = 0; i < 8; ++i) {
                        float4 rv = *(const float4*)(&Rs[w * 8 + i][c * KC + q * 4]);
                        #pragma unroll
                        for (int j = 0; j < 8; ++j) {
                            acc[i][j] = fmaf(rv.x, ev[j].x, acc[i][j]);
                            acc[i][j] = fmaf(rv.y, ev[j].y, acc[i][j]);
                            acc[i][j] = fmaf(rv.z, ev[j].z, acc[i][j]);
                            acc[i][j] = fmaf(rv.w, ev[j].w, acc[i][j]);
                        }
                    }
                }
            }

            float e2v[8];
            #pragma unroll
            for (int j = 0; j < 8; ++j)
                e2v[j] = e2g[s * KCODES + code0 + j * 64 + l];

            // ---- per-row top-1, numpy-exact dist & first-occurrence ties ----
            #pragma unroll
            for (int i = 0; i < 8; ++i) {
                float z2i = z2s[w * 8 + i];
                float m1 = 3.4e38f; int i1 = 0x7fffffff;
                #pragma unroll
                for (int j = 0; j < 8; ++j) {
                    float S = __fadd_rn(z2i, e2v[j]);      // fl(z2 + e2)
                    float v = fmaf(-2.f, acc[i][j], S);    // fl(S - 2*ze)
                    int cc = code0 + j * 64 + l;
                    if (v < m1) { m1 = v; i1 = cc; }       // ascending cc keeps first
                }
                #pragma unroll
                for (int d2 = 1; d2 < 64; d2 <<= 1) {
                    float ov = __shfl_xor(m1, d2); int oi = __shfl_xor(i1, d2);
                    if (ov < m1 || (ov == m1 && oi < i1)) { m1 = ov; i1 = oi; }
                }
                if (l == i) { top1v[p][w * 8 + i] = m1; top1i[p][w * 8 + i] = i1; }
            }
            __syncthreads();
        }

        // ---- merge passes (tie -> lower index = pass 0), emit code ----
        if (t < TM) {
            float av = top1v[0][t]; int ai = top1i[0][t];
            float bv = top1v[1][t]; int bi = top1i[1][t];
            int code = (bv < av) ? bi : ai;
            codes_s[t] = code;
            out[(size_t)BN * DDIM + (rowbase + t) * NQ + s] = (float)code;
        }
        __syncthreads();

        // ---- straight-through update, op-for-op numpy emulation (as r3) ----
        {
            int c = codes_s[row_u];
            const float4* crow = (const float4*)(cbs + (size_t)c * DDIM + oct * 32);
            float4* rrow = (float4*)(&Rs[row_u][oct * 32]);
            float z2n = 0.f;
            #pragma unroll
            for (int n = 0; n < 8; ++n) {
                int i = (n + t) & 7;              // rotate -> spread LDS banks
                float4 rv = rrow[i];
                float4 cv = crow[i];
                float t1x = __fsub_rn(cv.x, rv.x), t1y = __fsub_rn(cv.y, rv.y);
                float t1z = __fsub_rn(cv.z, rv.z), t1w = __fsub_rn(cv.w, rv.w);
                lacc += (double)t1x * t1x + (double)t1y * t1y
                      + (double)t1z * t1z + (double)t1w * t1w;
                float qx = __fadd_rn(rv.x, t1x), qy = __fadd_rn(rv.y, t1y);
                float qz = __fadd_rn(rv.z, t1z), qw = __fadd_rn(rv.w, t1w);
                float nx = __fsub_rn(rv.x, qx), ny = __fsub_rn(rv.y, qy);
                float nz = __fsub_rn(rv.z, qz), nw = __fsub_rn(rv.w, qw);
                z2n = fmaf(nx, nx, z2n); z2n = fmaf(ny, ny, z2n);
                z2n = fmaf(nz, nz, z2n); z2n = fmaf(nw, nw, z2n);
                rrow[i] = make_float4(nx, ny, nz, nw);
            }
            z2n += __shfl_xor(z2n, 1);
            z2n += __shfl_xor(z2n, 2);
            z2n += __shfl_xor(z2n, 4);
            if (oct == 0) z2s[row_u] = z2n;
        }
        __syncthreads();
    }

    // ---- z_q_sum = z_e - residual_final (telescoped; tolerance-validated) ----
    {
        const float4* zsrc = (const float4*)(zin + rowbase * DDIM);
        const float4* rsrc = (const float4*)(&Rs[0][0]);
        float4* dst = (float4*)(out + rowbase * DDIM);
        #pragma unroll
        for (int n = 0; n < (TM * DDIM / 4) / THREADS; ++n) {
            int idx = t + n * THREADS;
            float4 a = zsrc[idx], r = rsrc[idx];
            a.x -= r.x; a.y -= r.y; a.z -= r.z; a.w -= r.w;
            dst[idx] = a;
        }
    }

    // ---- deterministic per-block loss partial ----
    lred[t] = lacc;
    __syncthreads();
    if (t == 0) {
        double sum = 0.0;
        for (int i = 0; i < THREADS; ++i) sum += lred[i];
        lossp[blockIdx.x] = sum;
    }
}

__global__ void loss_final(const double* __restrict__ lossp, float* __restrict__ out) {
    double s = 0.0;
    for (int i = 0; i < BN / TM; ++i) s += lossp[i];
    out[(size_t)BN * DDIM + (size_t)BN * NQ] = (float)(1.25 * s / ((double)BN * (double)DDIM));
}

extern "C" void kernel_launch(void* const* d_in, const int* in_sizes, int n_in,
                              void* d_out, int out_size, void* d_ws, size_t ws_size,
                              hipStream_t stream) {
    const float* z_e = (const float*)d_in[0];
    const float* cb  = (const float*)d_in[1];
    float* out = (float*)d_out;
    float*  e2    = (float*)d_ws;                          // 8192 floats
    double* lossp = (double*)((char*)d_ws + 8192 * 4);     // 1024 doubles

    e2_kernel<<<dim3((NQ * KCODES) / 16), THREADS, 0, stream>>>(cb, e2);
    rq_kernel<<<dim3(BN / TM), THREADS, 0, stream>>>(z_e, cb, e2, out, lossp);
    loss_final<<<1, 1, 0, stream>>>(lossp, out);
}